// Round 3
// baseline (567.629 us; speedup 1.0000x reference)
//
#include <hip/hip_runtime.h>
#include <hip/hip_bf16.h>

#define NN 1048576
#define NG 16384
#define DD 128

typedef __bf16 bf16x8 __attribute__((ext_vector_type(8)));
typedef float f32x4 __attribute__((ext_vector_type(4)));
typedef unsigned short us8v __attribute__((ext_vector_type(8)));

__device__ __forceinline__ unsigned short f2bf(float f) {
    unsigned int u = __float_as_uint(f);
    u += 0x7FFFu + ((u >> 16) & 1u);
    return (unsigned short)(u >> 16);
}

__global__ void prep_kernel(const int* __restrict__ gid, const float* __restrict__ W,
                            int* __restrict__ starts, unsigned short* __restrict__ Wl) {
    int t = blockIdx.x * 256 + threadIdx.x;
    if (t <= NG) {
        int lo = 0, hi = NN;
        while (lo < hi) { int mid = (lo + hi) >> 1; if (gid[mid] < t) lo = mid + 1; else hi = mid; }
        starts[t] = lo;
    }
    if (t < DD * DD) {
        // fragment-ordered B layout: Wl[((n*4+kk)*64 + l)*8 + e] = bf16(W[k][col]),
        // k = kk*32 + (l>>4)*8 + e, col = n*16 + (l&15)
        int e = t & 7, l = (t >> 3) & 63, kk = (t >> 9) & 3, n = t >> 11;
        int k = kk * 32 + (l >> 4) * 8 + e;
        int col = n * 16 + (l & 15);
        Wl[t] = f2bf(W[k * DD + col]);
    }
}

// One graph per WAVE. No __syncthreads in the main loop; latency hidden by
// 12 independent wave-streams per CU (3 blocks x 4 waves).
__global__ __launch_bounds__(256, 3) void fused_kernel(
    const float* __restrict__ x, const int* __restrict__ starts,
    const unsigned short* __restrict__ Wl,
    const float* __restrict__ b_enc, const float* __restrict__ w_q1,
    const float* __restrict__ b_q1, const float* __restrict__ w_q2,
    const float* __restrict__ b_q2, float* __restrict__ out) {

    __shared__ unsigned short Wl_lds[DD * DD];   // 32 KB, fragment-ordered (lane-linear)

    const int t = threadIdx.x;
    const int w = t >> 6, l = t & 63;
    const int lr = l & 15, lk = l >> 4;

    for (int i = t; i < (DD * DD) / 8; i += 256)
        *(us8v*)&Wl_lds[i * 8] = *(const us8v*)&Wl[i * 8];

    float br[8], w1r[8], w2r[8];
#pragma unroll
    for (int n = 0; n < 8; ++n) {
        br[n]  = b_enc[n * 16 + lr];
        w1r[n] = w_q1[n * 16 + lr];
        w2r[n] = w_q2[n * 16 + lr];
    }
    const float bq1 = b_q1[0], bq2 = b_q2[0];
    __syncthreads();          // Wl_lds ready; no barriers after this point

    const int g = blockIdx.x * 4 + w;
    if (g >= NG) return;
    const int seg0 = starts[g], seg1 = starts[g + 1];
    const int cnt = seg1 - seg0;

    float m1 = -1e30f, m2 = -1e30f, z1 = 0.f, z2 = 0.f;
    float ka[8], q1a[8], q2a[8];
#pragma unroll
    for (int n = 0; n < 8; ++n) { ka[n] = 0.f; q1a[n] = 0.f; q2a[n] = 0.f; }

    if (cnt > 0) {
        float4 pf[8];
        {   // prefetch chunk 0: row = seg0 + lr, k-slice = lk*8 (+ kk*32)
            const int grow = seg0 + lr;
            const float* xp = x + (size_t)grow * DD + lk * 8;
            const bool v = grow < seg1;
            const float4 zz = {0.f, 0.f, 0.f, 0.f};
#pragma unroll
            for (int kk = 0; kk < 4; ++kk) {
                pf[2 * kk]     = v ? *(const float4*)(xp + kk * 32)     : zz;
                pf[2 * kk + 1] = v ? *(const float4*)(xp + kk * 32 + 4) : zz;
            }
        }

        for (int c0 = seg0; c0 < seg1; c0 += 16) {
            // ---- consume prefetch: fp32 -> bf16 A-fragments ----
            bf16x8 afr[4];
#pragma unroll
            for (int kk = 0; kk < 4; ++kk) {
                float4 a = pf[2 * kk], b2 = pf[2 * kk + 1];
                us8v uv;
                uv[0] = f2bf(a.x); uv[1] = f2bf(a.y); uv[2] = f2bf(a.z); uv[3] = f2bf(a.w);
                uv[4] = f2bf(b2.x); uv[5] = f2bf(b2.y); uv[6] = f2bf(b2.z); uv[7] = f2bf(b2.w);
                afr[kk] = __builtin_bit_cast(bf16x8, uv);
            }

            // ---- issue prefetch for next chunk ----
            if (c0 + 16 < seg1) {
                const int grow = c0 + 16 + lr;
                const float* xp = x + (size_t)grow * DD + lk * 8;
                const bool v = grow < seg1;
                const float4 zz = {0.f, 0.f, 0.f, 0.f};
#pragma unroll
                for (int kk = 0; kk < 4; ++kk) {
                    pf[2 * kk]     = v ? *(const float4*)(xp + kk * 32)     : zz;
                    pf[2 * kk + 1] = v ? *(const float4*)(xp + kk * 32 + 4) : zz;
                }
            }

            // ---- MFMA: h[16 x 128] for this wave's chunk ----
            f32x4 acc[8];
#pragma unroll
            for (int n = 0; n < 8; ++n) { acc[n][0] = 0.f; acc[n][1] = 0.f; acc[n][2] = 0.f; acc[n][3] = 0.f; }
#pragma unroll
            for (int n = 0; n < 8; ++n)
#pragma unroll
                for (int kk = 0; kk < 4; ++kk) {
                    bf16x8 bfr = *(const bf16x8*)&Wl_lds[((n * 4 + kk) * 64 + l) * 8];
                    acc[n] = __builtin_amdgcn_mfma_f32_16x16x32_bf16(afr[kk], bfr, acc[n], 0, 0, 0);
                }

            // ---- bias + relu; score partials (C layout: col=n*16+lr, row=lk*4+j) ----
            float p1[4] = {0.f, 0.f, 0.f, 0.f}, p2[4] = {0.f, 0.f, 0.f, 0.f};
#pragma unroll
            for (int n = 0; n < 8; ++n)
#pragma unroll
                for (int j = 0; j < 4; ++j) {
                    float hv = fmaxf(acc[n][j] + br[n], 0.f);
                    acc[n][j] = hv;
                    p1[j] += hv * w1r[n];
                    p2[j] += hv * w2r[n];
                }
            // butterfly over lr (bits 0..3): full 128-col dot, broadcast to group
#pragma unroll
            for (int j = 0; j < 4; ++j)
#pragma unroll
                for (int d = 1; d < 16; d <<= 1) {
                    p1[j] += __shfl_xor(p1[j], d);
                    p2[j] += __shfl_xor(p2[j], d);
                }

            // ---- chunk max over 16 rows: over j in-reg, then over lk (bits 4,5) ----
            float v1[4], v2[4];
            float r1 = -1e30f, r2 = -1e30f;
#pragma unroll
            for (int j = 0; j < 4; ++j) {
                const bool v = (c0 + lk * 4 + j) < seg1;
                v1[j] = v ? p1[j] + bq1 : -1e30f;
                v2[j] = v ? p2[j] + bq2 : -1e30f;
                r1 = fmaxf(r1, v1[j]); r2 = fmaxf(r2, v2[j]);
            }
            r1 = fmaxf(r1, __shfl_xor(r1, 16)); r1 = fmaxf(r1, __shfl_xor(r1, 32));
            r2 = fmaxf(r2, __shfl_xor(r2, 16)); r2 = fmaxf(r2, __shfl_xor(r2, 32));

            const float nm1 = fmaxf(m1, r1), nm2 = fmaxf(m2, r2);
            const float sc1 = __expf(m1 - nm1), sc2 = __expf(m2 - nm2);
            float e1j[4], e2j[4];
            float cz1 = 0.f, cz2 = 0.f;
#pragma unroll
            for (int j = 0; j < 4; ++j) {
                e1j[j] = __expf(v1[j] - nm1);      // invalid rows -> exp(-huge)=0
                e2j[j] = __expf(v2[j] - nm2);
                cz1 += e1j[j]; cz2 += e2j[j];
            }
            cz1 += __shfl_xor(cz1, 16); cz1 += __shfl_xor(cz1, 32);
            cz2 += __shfl_xor(cz2, 16); cz2 += __shfl_xor(cz2, 32);
            z1 = z1 * sc1 + cz1; z2 = z2 * sc2 + cz2;
            m1 = nm1; m2 = nm2;

            // ---- accumulate keys / q1 / q2 ----
#pragma unroll
            for (int n = 0; n < 8; ++n) {
                float kaa = 0.f, q1aa = 0.f, q2aa = 0.f;
#pragma unroll
                for (int j = 0; j < 4; ++j) {
                    const float hv = acc[n][j];
                    const bool v = (c0 + lk * 4 + j) < seg1;
                    kaa  += v ? hv : 0.f;
                    q1aa += e1j[j] * hv;
                    q2aa += e2j[j] * hv;
                }
                ka[n] += kaa;
                q1a[n] = q1a[n] * sc1 + q1aa;
                q2a[n] = q2a[n] * sc2 + q2aa;
            }
        }
    }

    // ---- reduce over lk (bits 4,5), broadcast, then write 2 cols/lane ----
#pragma unroll
    for (int n = 0; n < 8; ++n) {
#pragma unroll
        for (int d = 16; d < 64; d <<= 1) {
            ka[n]  += __shfl_xor(ka[n],  d);
            q1a[n] += __shfl_xor(q1a[n], d);
            q2a[n] += __shfl_xor(q2a[n], d);
        }
    }
    const float inv_cnt = 1.f / fmaxf((float)cnt, 1.f);
    const float iz1 = 1.f / fmaxf(z1, 1e-12f);
    const float iz2 = 1.f / fmaxf(z2, 1e-12f);
#pragma unroll
    for (int n2 = 0; n2 < 2; ++n2) {
        const int n = lk * 2 + n2;
        const int col = n * 16 + lr;
        out[(size_t)g * DD + col]            = ka[n]  * inv_cnt;
        out[(size_t)(NG + g) * DD + col]     = q1a[n] * iz1;
        out[(size_t)(2 * NG + g) * DD + col] = q2a[n] * iz2;
    }
}

extern "C" void kernel_launch(void* const* d_in, const int* in_sizes, int n_in,
                              void* d_out, int out_size, void* d_ws, size_t ws_size,
                              hipStream_t stream) {
    const float* x     = (const float*)d_in[0];
    const int*   gid   = (const int*)d_in[1];
    const float* W     = (const float*)d_in[2];
    const float* b_enc = (const float*)d_in[3];
    const float* w_q1  = (const float*)d_in[4];
    const float* b_q1  = (const float*)d_in[5];
    const float* w_q2  = (const float*)d_in[6];
    const float* b_q2  = (const float*)d_in[7];
    float* out = (float*)d_out;

    int* starts        = (int*)d_ws;                                // (NG+1) ints
    unsigned short* Wl = (unsigned short*)((char*)d_ws + 131072);   // 128*128 bf16, fragment-ordered

    prep_kernel<<<65, 256, 0, stream>>>(gid, W, starts, Wl);
    fused_kernel<<<NG / 4, 256, 0, stream>>>(x, starts, Wl, b_enc, w_q1, b_q1, w_q2, b_q2, out);
}